// Round 5
// baseline (8548.056 us; speedup 1.0000x reference)
//
#include <hip/hip_runtime.h>
#include <cstdint>
#include <cstddef>

namespace {

constexpr int H    = 300;
constexpr int G4   = 1200;   // 4*H
constexpr int B    = 128;
constexpr int T    = 512;
constexpr int NVOC = 2514;

// ---------------------------------------------------------------------------
// Tiled fp32 GEMM (unchanged; ~2.2 ms total, next round's target)
// ---------------------------------------------------------------------------
template<int AMODE, bool HASB2>
__global__ __launch_bounds__(256)
void gemm_tn(const float* __restrict__ A, const float* __restrict__ W,
             const float* __restrict__ b1, const float* __restrict__ b2,
             const int* __restrict__ tok, float* __restrict__ out, int N)
{
    constexpr int K = 300;
    __shared__ __align__(16) float as[8][128];
    __shared__ __align__(16) float bs[8][128];

    const int tid = threadIdx.x;
    const int tx = tid & 15, ty = tid >> 4;
    const int m0 = blockIdx.y * 128;
    const int n0 = blockIdx.x * 128;
    const int rl  = tid >> 1;
    const int kk0 = (tid & 1) * 4;

    const int m = m0 + rl;
    int arow;
    if (AMODE == 0) {
        arow = m;
    } else {
        const int q = ((m & 127) << 9) + (m >> 7);
        arow = (AMODE == 1) ? tok[q] : q;
    }
    const float* aptr = A + (size_t)arow * K;
    const int nrow = n0 + rl;
    const float* wptr = W + (size_t)nrow * K;
    const bool nvalid = (nrow < N);

    float acc[8][8];
#pragma unroll
    for (int i = 0; i < 8; ++i)
#pragma unroll
        for (int j = 0; j < 8; ++j) acc[i][j] = 0.f;

    for (int k0 = 0; k0 < K; k0 += 8) {
        float4 av = make_float4(0.f, 0.f, 0.f, 0.f);
        float4 bv = make_float4(0.f, 0.f, 0.f, 0.f);
        const bool kv = (k0 + kk0 < K);
        if (kv)           av = *(const float4*)(aptr + k0 + kk0);
        if (kv && nvalid) bv = *(const float4*)(wptr + k0 + kk0);
        __syncthreads();
        as[kk0+0][rl] = av.x; as[kk0+1][rl] = av.y; as[kk0+2][rl] = av.z; as[kk0+3][rl] = av.w;
        bs[kk0+0][rl] = bv.x; bs[kk0+1][rl] = bv.y; bs[kk0+2][rl] = bv.z; bs[kk0+3][rl] = bv.w;
        __syncthreads();
#pragma unroll
        for (int kk = 0; kk < 8; ++kk) {
            float4 a0 = *(const float4*)&as[kk][ty*8];
            float4 a1 = *(const float4*)&as[kk][ty*8+4];
            float4 c0 = *(const float4*)&bs[kk][tx*8];
            float4 c1 = *(const float4*)&bs[kk][tx*8+4];
            float a[8] = {a0.x,a0.y,a0.z,a0.w,a1.x,a1.y,a1.z,a1.w};
            float b[8] = {c0.x,c0.y,c0.z,c0.w,c1.x,c1.y,c1.z,c1.w};
#pragma unroll
            for (int i = 0; i < 8; ++i)
#pragma unroll
                for (int j = 0; j < 8; ++j)
                    acc[i][j] = fmaf(a[i], b[j], acc[i][j]);
        }
    }

    float bias[8];
#pragma unroll
    for (int j = 0; j < 8; ++j) {
        const int n = n0 + tx*8 + j;
        float v = 0.f;
        if (n < N) { v = b1[n]; if (HASB2) v += b2[n]; }
        bias[j] = v;
    }
#pragma unroll
    for (int i = 0; i < 8; ++i) {
        const int mi = m0 + ty*8 + i;
        float* orow = out + (size_t)mi * N + n0 + tx*8;
#pragma unroll
        for (int j = 0; j < 8; j += 2) {
            const int n = n0 + tx*8 + j;
            if (n + 1 < N) {
                *(float2*)(orow + j) = make_float2(acc[i][j] + bias[j],
                                                   acc[i][j+1] + bias[j+1]);
            } else if (n < N) {
                orow[j] = acc[i][j] + bias[j];
            }
        }
    }
}

// ---------------------------------------------------------------------------
// Sentinel fill (data-as-flag protocol, round-4 proven)
// ---------------------------------------------------------------------------
constexpr unsigned SENT = 0x7FB00F0Fu;   // quiet NaN payload; h in (-1,1) never NaN

__global__ __launch_bounds__(256)
void sentinel_fill(uint4* __restrict__ p, size_t n4)
{
    const uint4 s = make_uint4(SENT, SENT, SENT, SENT);
    size_t i = (size_t)blockIdx.x * blockDim.x + threadIdx.x;
    const size_t stride = (size_t)gridDim.x * blockDim.x;
    for (; i < n4; i += stride) p[i] = s;
}

// ---------------------------------------------------------------------------
// LSTM recurrence v5 — MFMA with W resident in VGPRs.
// 240 blocks = 15 hg x 16 bg, 256 threads, 1 block/CU -> 1 wave/SIMD ->
// full 512-VGPR budget per wave.
// Per step, per block: gates[8 batch][80 cols] = h[8][300] @ W^T via
// mfma_f32_16x16x32_bf16, split-precision (hi*hi + lo*hi + hi*lo), K pad 320.
// Roles: wave0 = MFMA ntiles 0-2 + gate update + h publish (240 B-frag VGPRs)
//        wave1 = MFMA ntiles 3-4 (160 B-frag VGPRs)
//        waves 2,3 = pollers: poll h[t-1] from global (8B relaxed agent
//          atomics vs sentinel), cvt to bf16 hi/lo, ds_write A-fragments in
//          MFMA layout into double-buffered Abuf[par].
// Handshakes = monotonic LDS flags (workgroup acquire/release = lgkmcnt only).
// No __syncthreads in the loop. Overwrite safety is inherent: h[t] of ANY
// block needs our h[t-1] (full H coupling), and our h[t-1] publish follows
// our A/gd reads in program order -> pollers can't clobber a buffer in use.
// ---------------------------------------------------------------------------
constexpr int HGC = 15;
constexpr int BGC = 16;
constexpr int NWG = HGC * BGC;   // 240

typedef __attribute__((ext_vector_type(8))) short  short8;
typedef __attribute__((ext_vector_type(4))) float  f32x4;

__device__ __forceinline__ float sigm(float x)     { return 1.f / (1.f + __expf(-x)); }
__device__ __forceinline__ float tanhfast(float x) { return 1.f - 2.f / (__expf(2.f*x) + 1.f); }

__device__ __forceinline__ unsigned short bf16_rn(float f) {
    unsigned u = __float_as_uint(f);
    u += 0x7FFFu + ((u >> 16) & 1u);
    return (unsigned short)(u >> 16);
}
__device__ __forceinline__ float bf16_f(unsigned short s) {
    return __uint_as_float(((unsigned)s) << 16);
}
__device__ __forceinline__ unsigned pack2(unsigned short lo16, unsigned short hi16) {
    return (unsigned)lo16 | ((unsigned)hi16 << 16);
}

// A-fragment LDS layout, per parity: [kt 0..9][half 0..1][kg 0..3][m 0..15][16B]
// byte offset = ((kt*2+half)*4 + kg)*256 + m*16 + dword*4        (20480 B/parity)
constexpr int APAR = 20480;

template<int NT0, int NTN, bool ISW0>
__device__ void compute_wave(int lane, int hg, int bg,
                             const float* __restrict__ xg,
                             const float* __restrict__ Whh,
                             float* __restrict__ h_all,
                             unsigned char (*Abuf)[APAR],
                             float (*gd)[80], int* lflags)
{
    const int kg = lane >> 4, mm = lane & 15;

    // ---- one-time: B fragments (hi/lo bf16) into registers ----
    // b-frag lane l holds W[n = nt*16 + (l&15)][k = kt*32 + (l>>4)*8 + j]
    short8 bh[10][NTN], bl[10][NTN];
#pragma unroll
    for (int kt = 0; kt < 10; ++kt) {
#pragma unroll
        for (int j = 0; j < NTN; ++j) {
            const int n    = (NT0 + j) * 16 + mm;
            const int grow = (n / 20) * H + hg * 20 + (n % 20);
            const int k0   = kt * 32 + kg * 8;
            short8 hi, lo;
#pragma unroll
            for (int q = 0; q < 8; ++q) {
                const int k = k0 + q;
                const float v = (k < H) ? Whh[(size_t)grow * H + k] : 0.f;
                const unsigned short h16 = bf16_rn(v);
                hi[q] = (short)h16;
                lo[q] = (short)bf16_rn(v - bf16_f(h16));
            }
            bh[kt][j] = hi; bl[kt][j] = lo;
        }
    }

    float cst[4] = {0.f, 0.f, 0.f, 0.f};   // cell state (wave0 lanes<40, 4 each)

    for (int t = 0; t < T; ++t) {
        // xg prefetch (global; lands during the waits below)
        float xv[4][4];
        if (ISW0 && lane < 40) {
#pragma unroll
            for (int r = 0; r < 4; ++r) {
                const int idx = lane + 40 * r, b = idx / 20, l = idx % 20;
                const float* xb = xg + ((size_t)t * B + bg * 8 + b) * G4 + hg * 20 + l;
#pragma unroll
                for (int g = 0; g < 4; ++g) xv[r][g] = xb[g * H];
            }
        }

        // wait for pollers to finish A[t&1]  (t=0: zero-init = h[-1]=0)
        if (t > 0) {
            while (__hip_atomic_load(&lflags[0], __ATOMIC_ACQUIRE,
                                     __HIP_MEMORY_SCOPE_WORKGROUP) < t ||
                   __hip_atomic_load(&lflags[1], __ATOMIC_ACQUIRE,
                                     __HIP_MEMORY_SCOPE_WORKGROUP) < t) {}
        }
        const unsigned char* Ab = Abuf[t & 1];

        f32x4 D[NTN];
#pragma unroll
        for (int j = 0; j < NTN; ++j) D[j] = (f32x4){0.f, 0.f, 0.f, 0.f};

#pragma unroll
        for (int kt = 0; kt < 10; ++kt) {
            const short8 ah = *(const short8*)(Ab + ((kt*2+0)*4 + kg)*256 + mm*16);
            const short8 al = *(const short8*)(Ab + ((kt*2+1)*4 + kg)*256 + mm*16);
#pragma unroll
            for (int j = 0; j < NTN; ++j) {
                D[j] = __builtin_amdgcn_mfma_f32_16x16x32_bf16(ah, bh[kt][j], D[j], 0, 0, 0);
                D[j] = __builtin_amdgcn_mfma_f32_16x16x32_bf16(al, bh[kt][j], D[j], 0, 0, 0);
                D[j] = __builtin_amdgcn_mfma_f32_16x16x32_bf16(ah, bl[kt][j], D[j], 0, 0, 0);
            }
        }

        // D[m][n]: n = nt*16 + (lane&15), m = (lane>>4)*4 + reg; valid m<8 -> lanes<32
        if (lane < 32) {
#pragma unroll
            for (int j = 0; j < NTN; ++j)
#pragma unroll
                for (int r = 0; r < 4; ++r)
                    gd[(lane >> 4) * 4 + r][(NT0 + j) * 16 + mm] = D[j][r];
        }

        if (!ISW0) {
            // wave1: publish gd portion, go wait for next A
            __hip_atomic_store(&lflags[2], t + 1, __ATOMIC_RELEASE,
                               __HIP_MEMORY_SCOPE_WORKGROUP);
        } else {
            // wave0: wait for wave1's gd, then gate update + h publish
            while (__hip_atomic_load(&lflags[2], __ATOMIC_ACQUIRE,
                                     __HIP_MEMORY_SCOPE_WORKGROUP) < t + 1) {}
            if (lane < 40) {
#pragma unroll
                for (int r = 0; r < 4; ++r) {
                    const int idx = lane + 40 * r, b = idx / 20, l = idx % 20;
                    const float gi = xv[r][0] + gd[b][     l];
                    const float gf = xv[r][1] + gd[b][20 + l];
                    const float gz = xv[r][2] + gd[b][40 + l];
                    const float go = xv[r][3] + gd[b][60 + l];
                    const float iG = sigm(gi), fG = sigm(gf);
                    const float zG = tanhfast(gz), oG = sigm(go);
                    cst[r] = fmaf(fG, cst[r], iG * zG);
                    const float hv = oG * tanhfast(cst[r]);
                    __hip_atomic_store(h_all + ((size_t)(bg*8 + b) * T + t) * H + hg*20 + l,
                                       hv, __ATOMIC_RELAXED, __HIP_MEMORY_SCOPE_AGENT);
                }
            }
        }
    }
}

__device__ void poller_wave(int pw, int lane, int bg,
                            const float* __restrict__ h_all,
                            unsigned char (*Abuf)[APAR], int* lflags)
{
    const int pl = pw * 64 + lane;         // 0..127
    // quad slots s = b*38 + kq  (8 batch x 38 k-quads of 8; kq37 half-valid)
    const float* qbase[3]; int offh[3], offl[3]; unsigned pend0 = 0; bool qok[3];
#pragma unroll
    for (int q = 0; q < 3; ++q) {
        const int s = pl + 128 * q;
        qok[q] = (s < 304);
        if (qok[q]) {
            const int b = s / 38, kq = s % 38;
            qbase[q] = h_all + (size_t)(bg*8 + b) * T * H + kq * 8;
            const int kt = kq >> 2, kgq = kq & 3;
            offh[q] = ((kt*2 + 0)*4 + kgq)*256 + b*16;
            offl[q] = ((kt*2 + 1)*4 + kgq)*256 + b*16;
            pend0 |= ((kq < 37) ? 0xFu : 0x3u) << (4*q);
        } else { qbase[q] = h_all; offh[q] = offl[q] = 0; }
    }

    for (int pt = 1; pt < T; ++pt) {
        float v[3][8];
#pragma unroll
        for (int q = 0; q < 3; ++q)
#pragma unroll
            for (int e = 0; e < 8; ++e) v[q][e] = 0.f;

        unsigned pend = pend0;
        const size_t toff = (size_t)(pt - 1) * H;
        while (__any(pend != 0)) {
#pragma unroll
            for (int q = 0; q < 3; ++q) {
#pragma unroll
                for (int j2 = 0; j2 < 4; ++j2) {
                    const unsigned bit = 1u << (4*q + j2);
                    if (pend & bit) {
                        const unsigned long long w = __hip_atomic_load(
                            (const unsigned long long*)(qbase[q] + toff) + j2,
                            __ATOMIC_RELAXED, __HIP_MEMORY_SCOPE_AGENT);
                        if ((unsigned)w != SENT && (unsigned)(w >> 32) != SENT) {
                            v[q][2*j2]   = __uint_as_float((unsigned)w);
                            v[q][2*j2+1] = __uint_as_float((unsigned)(w >> 32));
                            pend &= ~bit;
                        }
                    }
                }
            }
        }

        unsigned char* Ap = Abuf[pt & 1];
#pragma unroll
        for (int q = 0; q < 3; ++q) {
            if (qok[q]) {
                unsigned short h16[8]; uint4 hi, lo;
#pragma unroll
                for (int e = 0; e < 8; ++e) h16[e] = bf16_rn(v[q][e]);
                hi.x = pack2(h16[0], h16[1]); hi.y = pack2(h16[2], h16[3]);
                hi.z = pack2(h16[4], h16[5]); hi.w = pack2(h16[6], h16[7]);
                unsigned short l16[8];
#pragma unroll
                for (int e = 0; e < 8; ++e)
                    l16[e] = bf16_rn(v[q][e] - bf16_f(h16[e]));
                lo.x = pack2(l16[0], l16[1]); lo.y = pack2(l16[2], l16[3]);
                lo.z = pack2(l16[4], l16[5]); lo.w = pack2(l16[6], l16[7]);
                *(uint4*)(Ap + offh[q]) = hi;
                *(uint4*)(Ap + offl[q]) = lo;
            }
        }
        if (lane == 0)
            __hip_atomic_store(&lflags[pw], pt, __ATOMIC_RELEASE,
                               __HIP_MEMORY_SCOPE_WORKGROUP);
    }
}

__global__ __launch_bounds__(256, 1)
void lstm_mfma_k(const float* __restrict__ xg, const float* __restrict__ Whh,
                 float* __restrict__ h_all)
{
    __shared__ __align__(16) unsigned char Abuf[2][APAR];   // 40 KiB
    __shared__ __align__(16) float gd[8][80];               // 2.5 KiB
    __shared__ int lflags[16];

    const int tid = threadIdx.x, wv = tid >> 6, lane = tid & 63;
    const int hg = blockIdx.x % HGC, bg = blockIdx.x / HGC;

    // zero A (both parities: h[-1]=0 for t=0 + k/m pad) and flags
    for (int i = tid; i < 2 * APAR / 16; i += 256)
        ((uint4*)Abuf)[i] = make_uint4(0, 0, 0, 0);
    if (tid < 16) lflags[tid] = 0;
    __syncthreads();

    if      (wv == 0) compute_wave<0, 3, true >(lane, hg, bg, xg, Whh, h_all, Abuf, gd, lflags);
    else if (wv == 1) compute_wave<3, 2, false>(lane, hg, bg, xg, Whh, h_all, Abuf, gd, lflags);
    else              poller_wave(wv - 2, lane, bg, h_all, Abuf, lflags);
}

} // anonymous namespace

// ---------------------------------------------------------------------------
extern "C" void kernel_launch(void* const* d_in, const int* in_sizes, int n_in,
                              void* d_out, int out_size, void* d_ws, size_t ws_size,
                              hipStream_t stream)
{
    const int*   x    = (const int*)  d_in[0];
    const float* emb  = (const float*)d_in[1];
    const float* Wih0 = (const float*)d_in[2];
    const float* Whh0 = (const float*)d_in[3];
    const float* bih0 = (const float*)d_in[4];
    const float* bhh0 = (const float*)d_in[5];
    const float* Wih1 = (const float*)d_in[6];
    const float* Whh1 = (const float*)d_in[7];
    const float* bih1 = (const float*)d_in[8];
    const float* bhh1 = (const float*)d_in[9];
    const float* Wout = (const float*)d_in[10];
    const float* bout = (const float*)d_in[11];

    float* out = (float*)d_out;
    // xg [T][B][4H] fp32 (315 MB) aliases the output buffer (659 MB): fully
    // consumed before the final GEMM overwrites d_out.
    float* xg = (float*)d_out;
    float* h1 = (float*)d_ws;                       // [B][T][H] fp32, 78.6 MB
    float* h2 = h1 + (size_t)B * T * H;             // 78.6 MB

    // sentinel-fill both h buffers (data-as-flag protocol)
    const size_t nh = 2 * (size_t)B * T * H;
    sentinel_fill<<<dim3(2048), dim3(256), 0, stream>>>((uint4*)h1, nh / 4);

    const dim3 blk(256);
    // L0 input projection (embedding gather fused)
    gemm_tn<1, true ><<<dim3(10, 512), blk, 0, stream>>>(emb, Wih0, bih0, bhh0, x, xg, G4);
    // L0 recurrence
    lstm_mfma_k<<<dim3(NWG), blk, 0, stream>>>(xg, Whh0, h1);
    // L1 input projection ([b][t] -> [t][b] permute fused)
    gemm_tn<2, true ><<<dim3(10, 512), blk, 0, stream>>>(h1, Wih1, bih1, bhh1, nullptr, xg, G4);
    // L1 recurrence
    lstm_mfma_k<<<dim3(NWG), blk, 0, stream>>>(xg, Whh1, h2);
    // output projection -> logits [b*T+t][NVOC]
    gemm_tn<0, false><<<dim3(20, 512), blk, 0, stream>>>(h2, Wout, bout, nullptr, nullptr, out, NVOC);
}